// Round 2
// baseline (739.158 us; speedup 1.0000x reference)
//
#include <hip/hip_runtime.h>
#include <math.h>

// Problem constants (match reference)
#define BATCH 16384
#define DNUM  13
#define SNUM  26
#define FEAT  100000
#define KDIM  64          // = 16 float4 groups

// One 64-lane wave per batch row.
// lane = 16*q + t :  q = quarter (0..3), t = k-group (0..15), k in [4t, 4t+3].
// Sparse V gathers are float4: 16 lanes cover one V row (256 B), the wave
// covers 4 sparse rows per load group -> 7 wide loads instead of 26 scalar-k.
__global__ __launch_bounds__(256) void fm_kernel(
    const float*  __restrict__ dense,   // [B, D]
    const int*    __restrict__ sparse,  // [B, S]
    const float*  __restrict__ w,       // [TOTAL, 1]
    const float4* __restrict__ V4,      // [TOTAL, 16] (float4 view of [TOTAL, 64])
    const float*  __restrict__ bias,    // [1]
    float*        __restrict__ out)     // [B]
{
    const int wave = (blockIdx.x * blockDim.x + threadIdx.x) >> 6;
    const int lane = threadIdx.x & 63;
    if (wave >= BATCH) return;
    const int row = wave;
    const int q = lane >> 4;      // quarter
    const int t = lane & 15;      // k-group

    // Lanes 0..S-1 hold one global gather index each (coalesced idx load).
    int myidx = 0;
    if (lane < SNUM) {
        myidx = sparse[row * SNUM + lane] + DNUM + lane * FEAT;
    }

    float4 xv = make_float4(0.f, 0.f, 0.f, 0.f);  // partial xv for k in [4t,4t+3]
    float  x2 = 0.f;                              // partial sum_k x2v2 (linear, no fold needed)
    float  lin = 0.f;

    // ---- sparse second-order: 7 groups of 4 rows, quarter q takes row s = 4g+q ----
    #pragma unroll
    for (int g = 0; g < 7; ++g) {
        int s = g * 4 + q;
        if (s < SNUM) {
            int idx  = __shfl(myidx, s);                   // bpermute broadcast
            float4 v = V4[(long long)idx * 16 + t];        // coalesced 256B/row
            xv.x += v.x; xv.y += v.y; xv.z += v.z; xv.w += v.w;
            x2   += v.x * v.x + v.y * v.y + v.z * v.z + v.w * v.w;
        }
    }

    // ---- dense second-order: rows distributed over quarters, d = 4j+q ----
    #pragma unroll
    for (int j = 0; j < 4; ++j) {
        int d = j * 4 + q;
        if (d < DNUM) {
            float  xd = dense[row * DNUM + d];
            float4 v  = V4[d * 16 + t];                    // hot in L1 (13 rows)
            xv.x += xd * v.x; xv.y += xd * v.y;
            xv.z += xd * v.z; xv.w += xd * v.w;
            float xd2 = xd * xd;
            x2 += xd2 * (v.x * v.x + v.y * v.y + v.z * v.z + v.w * v.w);
        }
    }

    // ---- first-order (linear) term: sparse w on lanes 0..25, dense w on 26..38 ----
    if (lane < SNUM) {
        lin = w[myidx];
    } else if (lane < SNUM + DNUM) {
        int d = lane - SNUM;
        lin = dense[row * DNUM + d] * w[d];
    }

    // ---- fold the 4 quarters so each lane holds the COMPLETE xv for its 4 ks ----
    xv.x += __shfl_xor(xv.x, 16); xv.y += __shfl_xor(xv.y, 16);
    xv.z += __shfl_xor(xv.z, 16); xv.w += __shfl_xor(xv.w, 16);
    xv.x += __shfl_xor(xv.x, 32); xv.y += __shfl_xor(xv.y, 32);
    xv.z += __shfl_xor(xv.z, 32); xv.w += __shfl_xor(xv.w, 32);

    // Each k is now replicated in 4 lanes -> weight xv^2 by 0.5/4 = 0.125.
    float part = 0.125f * (xv.x * xv.x + xv.y * xv.y + xv.z * xv.z + xv.w * xv.w)
               - 0.5f * x2 + lin;

    // ---- 64-lane butterfly reduction ----
    #pragma unroll
    for (int off = 32; off > 0; off >>= 1)
        part += __shfl_down(part, off);

    if (lane == 0) {
        float z = part + bias[0];
        out[row] = 1.0f / (1.0f + expf(-z));
    }
}

extern "C" void kernel_launch(void* const* d_in, const int* in_sizes, int n_in,
                              void* d_out, int out_size, void* d_ws, size_t ws_size,
                              hipStream_t stream) {
    const float*  dense  = (const float*)d_in[0];
    const int*    sparse = (const int*)d_in[1];
    const float*  w      = (const float*)d_in[2];
    const float4* V4     = (const float4*)d_in[3];
    const float*  bias   = (const float*)d_in[4];
    float* out = (float*)d_out;

    const int waves_per_block = 256 / 64;
    const int grid = (BATCH + waves_per_block - 1) / waves_per_block;
    fm_kernel<<<grid, 256, 0, stream>>>(dense, sparse, w, V4, bias, out);
}

// Round 3
// 735.647 us; speedup vs baseline: 1.0048x; 1.0048x over previous
//
#include <hip/hip_runtime.h>
#include <math.h>

// Problem constants (match reference)
#define BATCH 16384
#define DNUM  13
#define SNUM  26
#define FEAT  100000
#define KDIM  64          // = 16 float4 groups
#define RPW   4           // rows per wave

// One 64-lane wave handles 4 batch rows.
// lane = 16*g + t : g = row group (0..3), t = k-group (0..15), k in [4t,4t+3].
// Each group issues 26 independent float4 gathers (one per sparse field) ->
// ~4x the in-flight bytes of the 1-row/wave version. Lane t fully owns its
// 4 latent dims, so no cross-group fold is needed; reduction is a 16-lane
// butterfly within the group.
__global__ __launch_bounds__(256, 4) void fm_kernel(
    const float*  __restrict__ dense,   // [B, D]
    const int*    __restrict__ sparse,  // [B, S]
    const float*  __restrict__ w,       // [TOTAL, 1]
    const float4* __restrict__ V4,      // [TOTAL, 16] (float4 view of [TOTAL, 64])
    const float*  __restrict__ bias,    // [1]
    float*        __restrict__ out)     // [B]
{
    const int wave = (blockIdx.x * blockDim.x + threadIdx.x) >> 6;
    const int lane = threadIdx.x & 63;
    const int g    = lane >> 4;     // row within wave
    const int t    = lane & 15;     // k-group
    const int row  = wave * RPW + g;         // BATCH = 4096 waves * 4, no tail
    const int sbase = row * SNUM;

    // ---- hoist all 26 gather indices (broadcast loads within group, L1-served) ----
    int idx[SNUM];
    #pragma unroll
    for (int s = 0; s < SNUM; ++s)
        idx[s] = sparse[sbase + s] + DNUM + s * FEAT;

    // ---- first-order term, issued early to overlap with V gathers ----
    // sparse w: lane t covers field t and t+16 (t<10); dense w: t<13.
    float lin = w[sparse[sbase + t] + DNUM + t * FEAT];
    if (t < SNUM - 16)
        lin += w[sparse[sbase + t + 16] + DNUM + (t + 16) * FEAT];
    const float* drow = dense + row * DNUM;
    if (t < DNUM)
        lin += drow[t] * w[t];

    // ---- sparse second-order: 26 independent coalesced float4 gathers ----
    float4 xv = make_float4(0.f, 0.f, 0.f, 0.f);
    float  x2 = 0.f;
    #pragma unroll
    for (int s = 0; s < SNUM; ++s) {
        float4 v = V4[idx[s] * 16 + t];
        xv.x += v.x; xv.y += v.y; xv.z += v.z; xv.w += v.w;
        x2   += v.x * v.x + v.y * v.y + v.z * v.z + v.w * v.w;
    }

    // ---- dense second-order: 13 rows, V[:13] hot in L1 ----
    #pragma unroll
    for (int d = 0; d < DNUM; ++d) {
        float  xd = drow[d];                 // broadcast within group
        float4 v  = V4[d * 16 + t];
        xv.x += xd * v.x; xv.y += xd * v.y;
        xv.z += xd * v.z; xv.w += xd * v.w;
        x2   += xd * xd * (v.x * v.x + v.y * v.y + v.z * v.z + v.w * v.w);
    }

    // ---- per-lane contribution: lane fully owns k in [4t, 4t+3] ----
    float part = 0.5f * (xv.x * xv.x + xv.y * xv.y + xv.z * xv.z + xv.w * xv.w - x2)
               + lin;

    // ---- 16-lane butterfly within the group (xor < 16 stays in-group) ----
    part += __shfl_xor(part, 1);
    part += __shfl_xor(part, 2);
    part += __shfl_xor(part, 4);
    part += __shfl_xor(part, 8);

    if (t == 0) {
        float z = part + bias[0];
        out[row] = 1.0f / (1.0f + expf(-z));
    }
}

extern "C" void kernel_launch(void* const* d_in, const int* in_sizes, int n_in,
                              void* d_out, int out_size, void* d_ws, size_t ws_size,
                              hipStream_t stream) {
    const float*  dense  = (const float*)d_in[0];
    const int*    sparse = (const int*)d_in[1];
    const float*  w      = (const float*)d_in[2];
    const float4* V4     = (const float4*)d_in[3];
    const float*  bias   = (const float*)d_in[4];
    float* out = (float*)d_out;

    // 4 rows/wave, 4 waves/block -> 16 rows/block; 1024 blocks = 4 blocks/CU.
    const int rows_per_block = (256 / 64) * RPW;
    const int grid = BATCH / rows_per_block;
    fm_kernel<<<grid, 256, 0, stream>>>(dense, sparse, w, V4, bias, out);
}